// Round 3
// baseline (2543.794 us; speedup 1.0000x reference)
//
#include <hip/hip_runtime.h>
#include <math.h>

#define BB 8
#define CC 192
#define NN 3136            // 56*56
#define NR 25088           // BB*NN
#define C2 384
#define GI 96
#define KNN 9
#define NCHUNK 256
#define RPC 98             // 256*98 = 25088
#define EPS_BN 1e-5f

typedef unsigned short ushortT;
typedef unsigned int uintT;
typedef _Float16 f16x8 __attribute__((ext_vector_type(8)));
typedef float f32x16 __attribute__((ext_vector_type(16)));

static __device__ __forceinline__ ushortT f16b(_Float16 v) {
  union { _Float16 f; ushortT u; } x; x.f = v; return x.u;
}

// ---------------- fc1: z[b,n,c] = sum_k x[b,k,n]*w1[c,k] + b1[c] ----------------
__global__ __launch_bounds__(256) void k_fc1(const float* __restrict__ x,
        const float* __restrict__ w1, const float* __restrict__ b1,
        float* __restrict__ z) {
  __shared__ __align__(16) float Xs[32*68];
  __shared__ __align__(16) float Ws[32*68];
  int b = blockIdx.z, n0 = blockIdx.x*64, c0 = blockIdx.y*64;
  int tid = threadIdx.x;
  int tcol = tid & 15, trow = tid >> 4;
  float acc[4][4] = {};
  const float4* xf4 = (const float4*)x;
  const float4* wf4 = (const float4*)w1;
  for (int kb = 0; kb < 6; ++kb) {
    int k0 = kb*32;
    __syncthreads();
    #pragma unroll
    for (int s = 0; s < 2; ++s) {
      int q = tid + 256*s;
      int kk = q >> 4, nq = q & 15;
      ((float4*)Xs)[kk*17 + nq] = xf4[(size_t)(b*CC + k0 + kk)*784 + (n0>>2) + nq];
    }
    #pragma unroll
    for (int s = 0; s < 2; ++s) {
      int q = tid + 256*s;
      int cc = q >> 3, kq = q & 7;
      float4 v = wf4[(size_t)(c0 + cc)*48 + (k0>>2) + kq];
      Ws[(kq*4+0)*68 + cc] = v.x;
      Ws[(kq*4+1)*68 + cc] = v.y;
      Ws[(kq*4+2)*68 + cc] = v.z;
      Ws[(kq*4+3)*68 + cc] = v.w;
    }
    __syncthreads();
    #pragma unroll 8
    for (int kk = 0; kk < 32; ++kk) {
      float4 a4 = ((const float4*)Xs)[kk*17 + trow];
      float4 b4 = ((const float4*)Ws)[kk*17 + tcol];
      float av[4] = {a4.x,a4.y,a4.z,a4.w};
      float bv[4] = {b4.x,b4.y,b4.z,b4.w};
      #pragma unroll
      for (int i = 0; i < 4; ++i)
        #pragma unroll
        for (int j = 0; j < 4; ++j)
          acc[i][j] += av[i]*bv[j];
    }
  }
  float4 bias = ((const float4*)b1)[(c0>>2) + tcol];
  float bb4[4] = {bias.x,bias.y,bias.z,bias.w};
  #pragma unroll
  for (int i = 0; i < 4; ++i) {
    int n = n0 + trow*4 + i;
    float4 o;
    o.x = acc[i][0] + bb4[0]; o.y = acc[i][1] + bb4[1];
    o.z = acc[i][2] + bb4[2]; o.w = acc[i][3] + bb4[3];
    ((float4*)z)[(size_t)(b*NN + n)*48 + (c0>>2) + tcol] = o;
  }
}

// ---------------- BN stats: deterministic 2-stage ----------------
__global__ void k_stats_part(const float* __restrict__ src, int C, float* __restrict__ part) {
  int c = threadIdx.x;        // blockDim.x == C
  int chunk = blockIdx.x;     // 0..255
  float s = 0.f, ss = 0.f;
  const float* p = src + (size_t)chunk*RPC*C + c;
  for (int r = 0; r < RPC; ++r) {
    float v = p[(size_t)r*C];
    s += v; ss += v*v;
  }
  part[(size_t)chunk*C + c] = s;
  part[(size_t)(NCHUNK + chunk)*C + c] = ss;
}

__global__ void k_stats_fin(const float* __restrict__ part, int C,
      const float* __restrict__ g, const float* __restrict__ be,
      float* __restrict__ scale, float* __restrict__ shift) {
  int c = threadIdx.x;
  float s = 0.f, ss = 0.f;
  for (int ch = 0; ch < NCHUNK; ++ch) {
    s  += part[(size_t)ch*C + c];
    ss += part[(size_t)(NCHUNK+ch)*C + c];
  }
  float mu = s / (float)NR;
  float var = ss/(float)NR - mu*mu;
  float rs = 1.0f / sqrtf(var + EPS_BN);
  float sc = g[c]*rs;
  scale[c] = sc;
  shift[c] = be[c] - mu*sc;
}

// ---- h = bn(z) in place; emit f16 split of f = h/||h|| (hi + lo*2^-12) and sqh = 0.5*sum f^2 ----
__global__ __launch_bounds__(256) void k_h_f(float* __restrict__ h,
      ushortT* __restrict__ fhi, ushortT* __restrict__ flo, float* __restrict__ sqh,
      const float* __restrict__ scale, const float* __restrict__ shift) {
  __shared__ __align__(16) float fbuf[4][192];
  int w = threadIdx.x >> 6, lane = threadIdx.x & 63;
  size_t row = (size_t)blockIdx.x*4 + w;
  float* hp = h + row*CC;
  float hv[3]; float s = 0.f;
  #pragma unroll
  for (int t = 0; t < 3; ++t) {
    int c = lane + 64*t;
    float v = hp[c]*scale[c] + shift[c];
    hv[t] = v; s += v*v;
  }
  #pragma unroll
  for (int o = 32; o; o >>= 1) s += __shfl_xor(s, o);
  float eta = fmaxf(sqrtf(s), 1e-12f);
  float fv[3]; float s2 = 0.f;
  #pragma unroll
  for (int t = 0; t < 3; ++t) { fv[t] = hv[t]/eta; s2 += fv[t]*fv[t]; }
  #pragma unroll
  for (int o = 32; o; o >>= 1) s2 += __shfl_xor(s2, o);
  #pragma unroll
  for (int t = 0; t < 3; ++t) {
    int c = lane + 64*t;
    hp[c] = hv[t];
    fbuf[w][c] = fv[t];
  }
  if (lane == 0) sqh[row] = 0.5f*s2;
  __syncthreads();
  // pack phase: 4 rows x 48 quad-channel units = 192 threads
  if (threadIdx.x < 192) {
    int r = threadIdx.x / 48, q = threadIdx.x % 48;
    size_t grow = (size_t)blockIdx.x*4 + r;
    float4 v = *(float4*)&fbuf[r][q*4];
    _Float16 a0=(_Float16)v.x, a1=(_Float16)v.y, a2=(_Float16)v.z, a3=(_Float16)v.w;
    float r0=v.x-(float)a0, r1=v.y-(float)a1, r2=v.z-(float)a2, r3=v.w-(float)a3;
    _Float16 b0=(_Float16)(r0*4096.f), b1=(_Float16)(r1*4096.f);
    _Float16 b2=(_Float16)(r2*4096.f), b3=(_Float16)(r3*4096.f);
    uintT hi0 = (uintT)f16b(a0) | ((uintT)f16b(a1)<<16);
    uintT hi1 = (uintT)f16b(a2) | ((uintT)f16b(a3)<<16);
    uintT lo0 = (uintT)f16b(b0) | ((uintT)f16b(b1)<<16);
    uintT lo1 = (uintT)f16b(b2) | ((uintT)f16b(b3)<<16);
    ((uint2*)(fhi + grow*CC))[q] = make_uint2(hi0, hi1);
    ((uint2*)(flo + grow*CC))[q] = make_uint2(lo0, lo1);
  }
}

// ---- fused pairwise-distance top-9 via f16-split MFMA; swapped operands put each row lane-local ----
// ranking key: d_eff = dot(f_j, f_r) - sq_j/2  (monotone inverse of dist; sq_r constant per row)
__global__ __launch_bounds__(256) void k_dist(const ushortT* __restrict__ fhi_,
     const ushortT* __restrict__ flo_, const float* __restrict__ sqh,
     int* __restrict__ idxg) {
  __shared__ __align__(16) float sqs[NN];          // 12544 B
  __shared__ float mgD[32][8][9];                  // 9216 B
  __shared__ int   mgI[32][8][9];                  // 9216 B
  int rt = blockIdx.x, b = blockIdx.y;
  int tid = threadIdx.x;
  int w = tid >> 6, lane = tid & 63;
  int l31 = lane & 31, kh = lane >> 5;

  for (int i = tid; i < NN/4; i += 256)
    ((float4*)sqs)[i] = ((const float4*)(sqh + (size_t)b*NN))[i];

  const f16x8* FH = (const f16x8*)(fhi_ + (size_t)b*NN*CC);  // row stride = 24 units
  const f16x8* FL = (const f16x8*)(flo_ + (size_t)b*NN*CC);
  int brow = rt*32 + l31;
  f16x8 Bh[12], Bl[12];
  #pragma unroll
  for (int ks = 0; ks < 12; ++ks) {
    Bh[ks] = FH[(size_t)brow*24 + ks*2 + kh];
    Bl[ks] = FL[(size_t)brow*24 + ks*2 + kh];
  }
  float TD[9]; int TI[9];
  #pragma unroll
  for (int t = 0; t < 9; ++t) { TD[t] = -3.0e38f; TI[t] = 0x7fffffff; }
  __syncthreads();

  for (int ct = w; ct < 98; ct += 4) {
    const f16x8* ArH = FH + (size_t)(ct*32 + l31)*24 + kh;
    const f16x8* ArL = FL + (size_t)(ct*32 + l31)*24 + kh;
    f32x16 acc, acc2;
    #pragma unroll
    for (int r = 0; r < 16; ++r) { acc[r] = 0.f; acc2[r] = 0.f; }
    {
      f16x8 Ah[12];
      #pragma unroll
      for (int ks = 0; ks < 12; ++ks) Ah[ks] = ArH[ks*2];
      #pragma unroll
      for (int ks = 0; ks < 12; ++ks) {
        acc  = __builtin_amdgcn_mfma_f32_32x32x16_f16(Ah[ks], Bh[ks], acc,  0, 0, 0);
        acc2 = __builtin_amdgcn_mfma_f32_32x32x16_f16(Ah[ks], Bl[ks], acc2, 0, 0, 0);
      }
    }
    {
      f16x8 Al[12];
      #pragma unroll
      for (int ks = 0; ks < 12; ++ks) Al[ks] = ArL[ks*2];
      #pragma unroll
      for (int ks = 0; ks < 12; ++ks)
        acc2 = __builtin_amdgcn_mfma_f32_32x32x16_f16(Al[ks], Bh[ks], acc2, 0, 0, 0);
    }
    int jb = ct*32 + 4*kh;
    float sqv[16];
    #pragma unroll
    for (int q = 0; q < 4; ++q) {
      float4 t4 = *(float4*)&sqs[jb + 8*q];
      sqv[4*q+0] = t4.x; sqv[4*q+1] = t4.y; sqv[4*q+2] = t4.z; sqv[4*q+3] = t4.w;
    }
    #pragma unroll
    for (int r = 0; r < 16; ++r) {
      float d = fmaf(acc2[r], 2.44140625e-4f, acc[r]) - sqv[r];
      int j = jb + (r&3) + 8*(r>>2);
      bool ins = (d > TD[0]) || (d == TD[0] && j < TI[0]);
      if (ins) {
        TD[0] = d; TI[0] = j;
        #pragma unroll
        for (int t = 0; t < 8; ++t) {
          bool sw = (TD[t] > TD[t+1]) || (TD[t] == TD[t+1] && TI[t] < TI[t+1]);
          if (sw) {
            float td = TD[t]; TD[t] = TD[t+1]; TD[t+1] = td;
            int ti = TI[t]; TI[t] = TI[t+1]; TI[t+1] = ti;
          }
        }
      }
    }
  }
  int slot = w*2 + kh;
  #pragma unroll
  for (int t = 0; t < 9; ++t) { mgD[l31][slot][t] = TD[t]; mgI[l31][slot][t] = TI[t]; }
  __syncthreads();
  if (tid < 32) {
    int r = tid;
    float MD[9]; int MI[9];
    #pragma unroll
    for (int t = 0; t < 9; ++t) { MD[t] = mgD[r][0][t]; MI[t] = mgI[r][0][t]; }
    for (int s2 = 1; s2 < 8; ++s2) {
      for (int t0 = 0; t0 < 9; ++t0) {
        float d = mgD[r][s2][t0]; int j = mgI[r][s2][t0];
        bool ins = (d > MD[0]) || (d == MD[0] && j < MI[0]);
        if (ins) {
          MD[0] = d; MI[0] = j;
          #pragma unroll
          for (int t = 0; t < 8; ++t) {
            bool sw = (MD[t] > MD[t+1]) || (MD[t] == MD[t+1] && MI[t] < MI[t+1]);
            if (sw) {
              float td = MD[t]; MD[t] = MD[t+1]; MD[t+1] = td;
              int ti = MI[t]; MI[t] = MI[t+1]; MI[t+1] = ti;
            }
          }
        }
      }
    }
    size_t base = ((size_t)b*NN + rt*32 + r)*KNN;
    #pragma unroll
    for (int t = 0; t < KNN; ++t) idxg[base + t] = MI[t];
  }
}

// ---------------- gather neighbors, rel = max_k h[idx_k] - h, interleave feat ----------------
__global__ __launch_bounds__(256) void k_gather(const float* __restrict__ h,
    const int* __restrict__ idxg, float* __restrict__ feat) {
  int w = threadIdx.x >> 6, lane = threadIdx.x & 63;
  size_t rg = (size_t)blockIdx.x*4 + w;
  int b = (int)(rg / NN);
  int n = (int)(rg % NN);
  const float* hb = h + (size_t)b*NN*CC;
  int j[KNN];
  #pragma unroll
  for (int t = 0; t < KNN; ++t) j[t] = idxg[rg*KNN + t];
  float2* featp = (float2*)feat;
  #pragma unroll
  for (int t = 0; t < 3; ++t) {
    int c = lane + 64*t;
    float self = hb[(size_t)n*CC + c];
    float m = -3.0e38f;
    #pragma unroll
    for (int k = 0; k < KNN; ++k) m = fmaxf(m, hb[(size_t)j[k]*CC + c]);
    featp[rg*CC + c] = make_float2(self, m - self);
  }
}

// ---------------- grouped conv ----------------
__global__ __launch_bounds__(256) void k_gconv(const float* __restrict__ feat,
   const float* __restrict__ wgc, const float* __restrict__ bgc, float* __restrict__ y) {
  __shared__ __align__(16) float Fs[64*100];
  __shared__ __align__(16) float Wsh[96*100];
  int rt = blockIdx.x, g = blockIdx.y;
  int tid = threadIdx.x, tc = tid & 15, tr = tid >> 4;
  const float4* f4p = (const float4*)feat;
  #pragma unroll
  for (int s = 0; s < 6; ++s) {
    int q = tid + 256*s; int r = q/24, kq = q - r*24;
    ((float4*)Fs)[r*25 + kq] = f4p[(size_t)(rt*64 + r)*96 + g*24 + kq];
  }
  #pragma unroll
  for (int s = 0; s < 9; ++s) {
    int q = tid + 256*s; int o = q/24, kq = q - o*24;
    ((float4*)Wsh)[o*25 + kq] = ((const float4*)wgc)[(size_t)(g*GI + o)*24 + kq];
  }
  __syncthreads();
  float acc[4][6] = {};
  #pragma unroll 4
  for (int k4 = 0; k4 < 24; ++k4) {
    float4 a[4], bv[6];
    #pragma unroll
    for (int i = 0; i < 4; ++i) a[i]  = ((const float4*)Fs)[(tr+16*i)*25 + k4];
    #pragma unroll
    for (int j = 0; j < 6; ++j) bv[j] = ((const float4*)Wsh)[(tc+16*j)*25 + k4];
    #pragma unroll
    for (int i = 0; i < 4; ++i)
      #pragma unroll
      for (int j = 0; j < 6; ++j)
        acc[i][j] += a[i].x*bv[j].x + a[i].y*bv[j].y + a[i].z*bv[j].z + a[i].w*bv[j].w;
  }
  #pragma unroll
  for (int j = 0; j < 6; ++j) {
    float bias = bgc[g*GI + tc + 16*j];
    #pragma unroll
    for (int i = 0; i < 4; ++i)
      y[(size_t)(rt*64 + tr + 16*i)*C2 + g*GI + tc + 16*j] = acc[i][j] + bias;
  }
}

// ---------------- bn + exact gelu, in place ----------------
__global__ void k_bn_gelu(float* __restrict__ y, const float* __restrict__ scale,
                          const float* __restrict__ shift) {
  size_t i = (size_t)blockIdx.x*blockDim.x + threadIdx.x;  // float4 index
  float4 v = ((float4*)y)[i];
  int c4 = (int)(i % 96);
  float4 sc = ((const float4*)scale)[c4], sh = ((const float4*)shift)[c4];
  float vv[4] = {v.x*sc.x+sh.x, v.y*sc.y+sh.y, v.z*sc.z+sh.z, v.w*sc.w+sh.w};
  #pragma unroll
  for (int t = 0; t < 4; ++t)
    vv[t] = 0.5f*vv[t]*(1.0f + erff(vv[t]*0.70710678118654752440f));
  v.x = vv[0]; v.y = vv[1]; v.z = vv[2]; v.w = vv[3];
  ((float4*)y)[i] = v;
}

// ---------------- fc2 ----------------
__global__ __launch_bounds__(256) void k_fc2(const float* __restrict__ y2,
    const float* __restrict__ w2, const float* __restrict__ b2, float* __restrict__ op) {
  __shared__ __align__(16) float As[64*68];
  __shared__ __align__(16) float Wsh[64*68];
  int rt = blockIdx.x, c0 = blockIdx.y*64;
  int tid = threadIdx.x, tc = tid & 15, tr = tid >> 4;
  float acc[4][4] = {};
  for (int kc = 0; kc < 6; ++kc) {
    __syncthreads();
    #pragma unroll
    for (int s = 0; s < 4; ++s) {
      int q = tid + 256*s;
      int r = q >> 4, kq = q & 15;
      ((float4*)As)[r*17 + kq]  = ((const float4*)y2)[(size_t)(rt*64 + r)*96 + kc*16 + kq];
      ((float4*)Wsh)[r*17 + kq] = ((const float4*)w2)[(size_t)(c0 + r)*96 + kc*16 + kq];
    }
    __syncthreads();
    #pragma unroll 4
    for (int k4 = 0; k4 < 16; ++k4) {
      float4 a[4], bv[4];
      #pragma unroll
      for (int i = 0; i < 4; ++i) a[i]  = ((const float4*)As)[(tr+16*i)*17 + k4];
      #pragma unroll
      for (int j = 0; j < 4; ++j) bv[j] = ((const float4*)Wsh)[(tc+16*j)*17 + k4];
      #pragma unroll
      for (int i = 0; i < 4; ++i)
        #pragma unroll
        for (int j = 0; j < 4; ++j)
          acc[i][j] += a[i].x*bv[j].x + a[i].y*bv[j].y + a[i].z*bv[j].z + a[i].w*bv[j].w;
    }
  }
  #pragma unroll
  for (int j = 0; j < 4; ++j) {
    float bias = b2[c0 + tc + 16*j];
    #pragma unroll
    for (int i = 0; i < 4; ++i)
      op[(size_t)(rt*64 + tr + 16*i)*CC + c0 + tc + 16*j] = acc[i][j] + bias;
  }
}

// ---------------- final bn + residual + transpose to (B,C,N) ----------------
__global__ __launch_bounds__(256) void k_final(const float* __restrict__ op,
    const float* __restrict__ x, const float* __restrict__ scale,
    const float* __restrict__ shift, float* __restrict__ out) {
  __shared__ float t[32][33];
  int n0 = blockIdx.x*32, c0 = blockIdx.y*32, b = blockIdx.z;
  int tx = threadIdx.x, ty = threadIdx.y;
  #pragma unroll
  for (int s = 0; s < 4; ++s) {
    int r = ty + 8*s;
    int c = c0 + tx;
    t[r][tx] = op[((size_t)b*NN + n0 + r)*CC + c]*scale[c] + shift[c];
  }
  __syncthreads();
  #pragma unroll
  for (int s = 0; s < 4; ++s) {
    int c = ty + 8*s;
    size_t o = ((size_t)b*CC + c0 + c)*NN + n0 + tx;
    out[o] = t[tx][c] + x[o];
  }
}

extern "C" void kernel_launch(void* const* d_in, const int* in_sizes, int n_in,
                              void* d_out, int out_size, void* d_ws, size_t ws_size,
                              hipStream_t stream) {
  (void)in_sizes; (void)n_in; (void)out_size; (void)ws_size;
  const float* x   = (const float*)d_in[0];
  const float* w1  = (const float*)d_in[1];
  const float* b1  = (const float*)d_in[2];
  const float* g1  = (const float*)d_in[3];
  const float* be1 = (const float*)d_in[4];
  const float* wgc = (const float*)d_in[5];
  const float* bgc = (const float*)d_in[6];
  const float* g2  = (const float*)d_in[7];
  const float* be2 = (const float*)d_in[8];
  const float* w2  = (const float*)d_in[9];
  const float* b2  = (const float*)d_in[10];
  const float* g3  = (const float*)d_in[11];
  const float* be3 = (const float*)d_in[12];
  float* ws = (float*)d_ws;

  // Workspace (floats):
  // h:   [0, 4816896)                 z -> h in place; later reused as op
  // fhi: [4816896, 7225344)           f16 hi (2,408,448 f32 slots = 4.8M ushorts)
  // flo: [7225344, 9633792)           f16 lo (scaled 2^12)
  // feat:[4816896, 14450688)          aliases fhi/flo (dead after k_dist)
  // sqh: [14450688, 14475776)
  // idx: [14475776, 14701568)
  // part:[14701568, 14898176)
  // st:  [14898176, 14899712)
  float* h    = ws;
  ushortT* fhi = (ushortT*)(ws + 4816896);
  ushortT* flo = (ushortT*)(ws + 7225344);
  float* feat = ws + 4816896;
  float* op   = ws;                        // alias of h region (h dead after k_gather)
  float* sqh  = ws + 14450688;
  int*   idx  = (int*)(ws + 14475776);
  float* part = ws + 14701568;
  float* st   = ws + 14898176;
  float* sc1 = st;        float* sh1 = st + 192;
  float* sc2 = st + 384;  float* sh2 = st + 768;
  float* sc3 = st + 1152; float* sh3 = st + 1344;
  float* out = (float*)d_out;

  k_fc1<<<dim3(49,3,8), 256, 0, stream>>>(x, w1, b1, h);
  k_stats_part<<<NCHUNK, CC, 0, stream>>>(h, CC, part);
  k_stats_fin<<<1, CC, 0, stream>>>(part, CC, g1, be1, sc1, sh1);
  k_h_f<<<NR/4, 256, 0, stream>>>(h, fhi, flo, sqh, sc1, sh1);
  k_dist<<<dim3(98,8), 256, 0, stream>>>(fhi, flo, sqh, idx);
  k_gather<<<NR/4, 256, 0, stream>>>(h, idx, feat);
  k_gconv<<<dim3(392,4), 256, 0, stream>>>(feat, wgc, bgc, feat);   // y in place
  k_stats_part<<<NCHUNK, C2, 0, stream>>>(feat, C2, part);
  k_stats_fin<<<1, C2, 0, stream>>>(part, C2, g2, be2, sc2, sh2);
  k_bn_gelu<<<9408, 256, 0, stream>>>(feat, sc2, sh2);
  k_fc2<<<dim3(392,3), 256, 0, stream>>>(feat, w2, b2, op);
  k_stats_part<<<NCHUNK, CC, 0, stream>>>(op, CC, part);
  k_stats_fin<<<1, CC, 0, stream>>>(part, CC, g3, be3, sc3, sh3);
  k_final<<<dim3(98,6,8), dim3(32,8), 0, stream>>>(op, x, sc3, sh3, out);
}

// Round 4
// 1660.648 us; speedup vs baseline: 1.5318x; 1.5318x over previous
//
#include <hip/hip_runtime.h>
#include <math.h>

#define BB 8
#define CC 192
#define NN 3136            // 56*56
#define NR 25088           // BB*NN
#define C2 384
#define GI 96
#define KNN 9
#define NCHUNK 256
#define RPC 98             // 256*98 = 25088
#define EPS_BN 1e-5f

typedef unsigned short ushortT;
typedef unsigned int uintT;
typedef _Float16 f16x8 __attribute__((ext_vector_type(8)));
typedef float f32x16 __attribute__((ext_vector_type(16)));

static __device__ __forceinline__ ushortT f16b(_Float16 v) {
  union { _Float16 f; ushortT u; } x; x.f = v; return x.u;
}

// ---------------- fc1: z[b,n,c] = sum_k x[b,k,n]*w1[c,k] + b1[c] ----------------
__global__ __launch_bounds__(256) void k_fc1(const float* __restrict__ x,
        const float* __restrict__ w1, const float* __restrict__ b1,
        float* __restrict__ z) {
  __shared__ __align__(16) float Xs[32*68];
  __shared__ __align__(16) float Ws[32*68];
  int b = blockIdx.z, n0 = blockIdx.x*64, c0 = blockIdx.y*64;
  int tid = threadIdx.x;
  int tcol = tid & 15, trow = tid >> 4;
  float acc[4][4] = {};
  const float4* xf4 = (const float4*)x;
  const float4* wf4 = (const float4*)w1;
  for (int kb = 0; kb < 6; ++kb) {
    int k0 = kb*32;
    __syncthreads();
    #pragma unroll
    for (int s = 0; s < 2; ++s) {
      int q = tid + 256*s;
      int kk = q >> 4, nq = q & 15;
      ((float4*)Xs)[kk*17 + nq] = xf4[(size_t)(b*CC + k0 + kk)*784 + (n0>>2) + nq];
    }
    #pragma unroll
    for (int s = 0; s < 2; ++s) {
      int q = tid + 256*s;
      int cc = q >> 3, kq = q & 7;
      float4 v = wf4[(size_t)(c0 + cc)*48 + (k0>>2) + kq];
      Ws[(kq*4+0)*68 + cc] = v.x;
      Ws[(kq*4+1)*68 + cc] = v.y;
      Ws[(kq*4+2)*68 + cc] = v.z;
      Ws[(kq*4+3)*68 + cc] = v.w;
    }
    __syncthreads();
    #pragma unroll 8
    for (int kk = 0; kk < 32; ++kk) {
      float4 a4 = ((const float4*)Xs)[kk*17 + trow];
      float4 b4 = ((const float4*)Ws)[kk*17 + tcol];
      float av[4] = {a4.x,a4.y,a4.z,a4.w};
      float bv[4] = {b4.x,b4.y,b4.z,b4.w};
      #pragma unroll
      for (int i = 0; i < 4; ++i)
        #pragma unroll
        for (int j = 0; j < 4; ++j)
          acc[i][j] += av[i]*bv[j];
    }
  }
  float4 bias = ((const float4*)b1)[(c0>>2) + tcol];
  float bb4[4] = {bias.x,bias.y,bias.z,bias.w};
  #pragma unroll
  for (int i = 0; i < 4; ++i) {
    int n = n0 + trow*4 + i;
    float4 o;
    o.x = acc[i][0] + bb4[0]; o.y = acc[i][1] + bb4[1];
    o.z = acc[i][2] + bb4[2]; o.w = acc[i][3] + bb4[3];
    ((float4*)z)[(size_t)(b*NN + n)*48 + (c0>>2) + tcol] = o;
  }
}

// ---------------- BN stats: deterministic 2-stage ----------------
__global__ void k_stats_part(const float* __restrict__ src, int C, float* __restrict__ part) {
  int c = threadIdx.x;        // blockDim.x == C
  int chunk = blockIdx.x;     // 0..255
  float s = 0.f, ss = 0.f;
  const float* p = src + (size_t)chunk*RPC*C + c;
  for (int r = 0; r < RPC; ++r) {
    float v = p[(size_t)r*C];
    s += v; ss += v*v;
  }
  part[(size_t)chunk*C + c] = s;
  part[(size_t)(NCHUNK + chunk)*C + c] = ss;
}

__global__ void k_stats_fin(const float* __restrict__ part, int C,
      const float* __restrict__ g, const float* __restrict__ be,
      float* __restrict__ scale, float* __restrict__ shift) {
  int c = threadIdx.x;
  float s = 0.f, ss = 0.f;
  for (int ch = 0; ch < NCHUNK; ++ch) {
    s  += part[(size_t)ch*C + c];
    ss += part[(size_t)(NCHUNK+ch)*C + c];
  }
  float mu = s / (float)NR;
  float var = ss/(float)NR - mu*mu;
  float rs = 1.0f / sqrtf(var + EPS_BN);
  float sc = g[c]*rs;
  scale[c] = sc;
  shift[c] = be[c] - mu*sc;
}

// ---- h = bn(z) in place; emit f16 split of f = h/||h|| (hi + lo*2^-12) and sqh = 0.5*sum f^2 ----
__global__ __launch_bounds__(256) void k_h_f(float* __restrict__ h,
      ushortT* __restrict__ fhi, ushortT* __restrict__ flo, float* __restrict__ sqh,
      const float* __restrict__ scale, const float* __restrict__ shift) {
  __shared__ __align__(16) float fbuf[4][192];
  int w = threadIdx.x >> 6, lane = threadIdx.x & 63;
  size_t row = (size_t)blockIdx.x*4 + w;
  float* hp = h + row*CC;
  float hv[3]; float s = 0.f;
  #pragma unroll
  for (int t = 0; t < 3; ++t) {
    int c = lane + 64*t;
    float v = hp[c]*scale[c] + shift[c];
    hv[t] = v; s += v*v;
  }
  #pragma unroll
  for (int o = 32; o; o >>= 1) s += __shfl_xor(s, o);
  float eta = fmaxf(sqrtf(s), 1e-12f);
  float fv[3]; float s2 = 0.f;
  #pragma unroll
  for (int t = 0; t < 3; ++t) { fv[t] = hv[t]/eta; s2 += fv[t]*fv[t]; }
  #pragma unroll
  for (int o = 32; o; o >>= 1) s2 += __shfl_xor(s2, o);
  #pragma unroll
  for (int t = 0; t < 3; ++t) {
    int c = lane + 64*t;
    hp[c] = hv[t];
    fbuf[w][c] = fv[t];
  }
  if (lane == 0) sqh[row] = 0.5f*s2;
  __syncthreads();
  // pack phase: 4 rows x 48 quad-channel units = 192 threads
  if (threadIdx.x < 192) {
    int r = threadIdx.x / 48, q = threadIdx.x % 48;
    size_t grow = (size_t)blockIdx.x*4 + r;
    float4 v = *(float4*)&fbuf[r][q*4];
    _Float16 a0=(_Float16)v.x, a1=(_Float16)v.y, a2=(_Float16)v.z, a3=(_Float16)v.w;
    float r0=v.x-(float)a0, r1=v.y-(float)a1, r2=v.z-(float)a2, r3=v.w-(float)a3;
    _Float16 b0=(_Float16)(r0*4096.f), b1=(_Float16)(r1*4096.f);
    _Float16 b2=(_Float16)(r2*4096.f), b3=(_Float16)(r3*4096.f);
    uintT hi0 = (uintT)f16b(a0) | ((uintT)f16b(a1)<<16);
    uintT hi1 = (uintT)f16b(a2) | ((uintT)f16b(a3)<<16);
    uintT lo0 = (uintT)f16b(b0) | ((uintT)f16b(b1)<<16);
    uintT lo1 = (uintT)f16b(b2) | ((uintT)f16b(b3)<<16);
    ((uint2*)(fhi + grow*CC))[q] = make_uint2(hi0, hi1);
    ((uint2*)(flo + grow*CC))[q] = make_uint2(lo0, lo1);
  }
}

// ---- pairwise-distance top-9: LDS-staged candidates, full sweep per wave ----
// Block owns 128 rows (wave w: rows rt*128+w*32 .. +31, B-operand in regs).
// Candidates chunked 32-wide, double-buffered in LDS (XOR-swizzled), shared by all 4 waves.
// ranking key: d_eff = dot(f_j, f_r) - sq_j/2 (larger = closer); per-lane top-9, 2-way kh merge.
__global__ __launch_bounds__(256) void k_dist(const ushortT* __restrict__ fhi_,
     const ushortT* __restrict__ flo_, const float* __restrict__ sqh,
     int* __restrict__ idxg) {
  __shared__ __align__(16) f16x8 AHs[2][768];   // 2 x 32 rows x 24 units (16B) = 24 KB
  __shared__ __align__(16) f16x8 ALs[2][768];   // 24 KB
  __shared__ float sqs[NN];                     // 12.5 KB
  int id = blockIdx.x;
  int b = id & 7, rt = id >> 3;                 // XCD-affine: batch == id%8
  int tid = threadIdx.x;
  int w = tid >> 6, lane = tid & 63;
  int l31 = lane & 31, kh = lane >> 5;

  for (int i = tid; i < NN/4; i += 256)
    ((float4*)sqs)[i] = ((const float4*)(sqh + (size_t)b*NN))[i];

  const f16x8* FH = (const f16x8*)(fhi_ + (size_t)b*NN*CC);  // row stride = 24 units
  const f16x8* FL = (const f16x8*)(flo_ + (size_t)b*NN*CC);

  int myrow = rt*128 + w*32 + l31;
  int brow = myrow < NN ? myrow : NN-1;
  f16x8 Bh[12], Bl[12];
  #pragma unroll
  for (int ks = 0; ks < 12; ++ks) {
    Bh[ks] = FH[(size_t)brow*24 + ks*2 + kh];
    Bl[ks] = FL[(size_t)brow*24 + ks*2 + kh];
  }

  // stage chunk 0 into buffer 0 (coalesced; XOR swizzle u^(row&7) within 8-unit groups)
  #pragma unroll
  for (int i = 0; i < 3; ++i) {
    int q = tid + 256*i; int row = q/24, u = q - row*24;
    AHs[0][row*24 + (u ^ (row&7))] = FH[(size_t)row*24 + u];
    ALs[0][row*24 + (u ^ (row&7))] = FL[(size_t)row*24 + u];
  }

  float TD[9]; int TI[9];
  #pragma unroll
  for (int t = 0; t < 9; ++t) { TD[t] = -3.0e38f; TI[t] = 0x7fffffff; }

  for (int ct = 0; ct < 98; ++ct) {
    __syncthreads();
    int buf = ct & 1;
    // issue next-chunk global loads early (latency hidden under MFMA)
    f16x8 sh[3], sl[3]; int srow[3], su[3];
    bool has = (ct + 1) < 98;
    if (has) {
      #pragma unroll
      for (int i = 0; i < 3; ++i) {
        int q = tid + 256*i; int row = q/24, u = q - row*24;
        srow[i] = row; su[i] = u;
        sh[i] = FH[(size_t)((ct+1)*32 + row)*24 + u];
        sl[i] = FL[(size_t)((ct+1)*32 + row)*24 + u];
      }
    }
    f32x16 acc, acc2;
    #pragma unroll
    for (int r = 0; r < 16; ++r) { acc[r] = 0.f; acc2[r] = 0.f; }
    {
      f16x8 Ah[12];
      #pragma unroll
      for (int ks = 0; ks < 12; ++ks)
        Ah[ks] = AHs[buf][l31*24 + (((ks*2+kh)) ^ (l31&7))];
      #pragma unroll
      for (int ks = 0; ks < 12; ++ks) {
        acc  = __builtin_amdgcn_mfma_f32_32x32x16_f16(Ah[ks], Bh[ks], acc,  0, 0, 0);
        acc2 = __builtin_amdgcn_mfma_f32_32x32x16_f16(Ah[ks], Bl[ks], acc2, 0, 0, 0);
      }
    }
    {
      f16x8 Al2[12];
      #pragma unroll
      for (int ks = 0; ks < 12; ++ks)
        Al2[ks] = ALs[buf][l31*24 + (((ks*2+kh)) ^ (l31&7))];
      #pragma unroll
      for (int ks = 0; ks < 12; ++ks)
        acc2 = __builtin_amdgcn_mfma_f32_32x32x16_f16(Al2[ks], Bh[ks], acc2, 0, 0, 0);
    }
    // selection: lane owns row l31 (of wave w), candidates m = 4*kh + (r&3) + 8*(r>>2)
    int jb = ct*32 + 4*kh;
    float sqv[16];
    #pragma unroll
    for (int q = 0; q < 4; ++q) {
      float4 t4 = *(float4*)&sqs[jb + 8*q];
      sqv[4*q+0] = t4.x; sqv[4*q+1] = t4.y; sqv[4*q+2] = t4.z; sqv[4*q+3] = t4.w;
    }
    #pragma unroll
    for (int r = 0; r < 16; ++r) {
      float d = fmaf(acc2[r], 2.44140625e-4f, acc[r]) - sqv[r];
      int j = jb + (r&3) + 8*(r>>2);
      bool ins = (d > TD[0]) || (d == TD[0] && j < TI[0]);
      if (ins) {
        TD[0] = d; TI[0] = j;
        #pragma unroll
        for (int t = 0; t < 8; ++t) {
          bool sw = (TD[t] > TD[t+1]) || (TD[t] == TD[t+1] && TI[t] < TI[t+1]);
          if (sw) {
            float td = TD[t]; TD[t] = TD[t+1]; TD[t+1] = td;
            int ti = TI[t]; TI[t] = TI[t+1]; TI[t+1] = ti;
          }
        }
      }
    }
    // write next chunk into other buffer (drained by next barrier)
    if (has) {
      #pragma unroll
      for (int i = 0; i < 3; ++i) {
        AHs[buf^1][srow[i]*24 + (su[i] ^ (srow[i]&7))] = sh[i];
        ALs[buf^1][srow[i]*24 + (su[i] ^ (srow[i]&7))] = sl[i];
      }
    }
  }

  // 2-way merge: kh=0 lane pulls kh=1 partial list for the same row via shuffle
  #pragma unroll
  for (int t = 0; t < 9; ++t) {
    float od = __shfl(TD[t], l31 + 32);
    int   oj = __shfl(TI[t], l31 + 32);
    bool ins = (od > TD[0]) || (od == TD[0] && oj < TI[0]);
    if (ins) {
      TD[0] = od; TI[0] = oj;
      #pragma unroll
      for (int t2 = 0; t2 < 8; ++t2) {
        bool sw = (TD[t2] > TD[t2+1]) || (TD[t2] == TD[t2+1] && TI[t2] < TI[t2+1]);
        if (sw) {
          float td = TD[t2]; TD[t2] = TD[t2+1]; TD[t2+1] = td;
          int ti = TI[t2]; TI[t2] = TI[t2+1]; TI[t2+1] = ti;
        }
      }
    }
  }
  if (kh == 0 && myrow < NN) {
    size_t base = ((size_t)b*NN + myrow)*KNN;
    #pragma unroll
    for (int t = 0; t < KNN; ++t) idxg[base + t] = TI[t];
  }
}

// ---------------- gather neighbors, rel = max_k h[idx_k] - h, interleave feat ----------------
__global__ __launch_bounds__(256) void k_gather(const float* __restrict__ h,
    const int* __restrict__ idxg, float* __restrict__ feat) {
  int w = threadIdx.x >> 6, lane = threadIdx.x & 63;
  size_t rg = (size_t)blockIdx.x*4 + w;
  int b = (int)(rg / NN);
  int n = (int)(rg % NN);
  const float* hb = h + (size_t)b*NN*CC;
  int j[KNN];
  #pragma unroll
  for (int t = 0; t < KNN; ++t) j[t] = idxg[rg*KNN + t];
  float2* featp = (float2*)feat;
  #pragma unroll
  for (int t = 0; t < 3; ++t) {
    int c = lane + 64*t;
    float self = hb[(size_t)n*CC + c];
    float m = -3.0e38f;
    #pragma unroll
    for (int k = 0; k < KNN; ++k) m = fmaxf(m, hb[(size_t)j[k]*CC + c]);
    featp[rg*CC + c] = make_float2(self, m - self);
  }
}

// ---------------- grouped conv ----------------
__global__ __launch_bounds__(256) void k_gconv(const float* __restrict__ feat,
   const float* __restrict__ wgc, const float* __restrict__ bgc, float* __restrict__ y) {
  __shared__ __align__(16) float Fs[64*100];
  __shared__ __align__(16) float Wsh[96*100];
  int rt = blockIdx.x, g = blockIdx.y;
  int tid = threadIdx.x, tc = tid & 15, tr = tid >> 4;
  const float4* f4p = (const float4*)feat;
  #pragma unroll
  for (int s = 0; s < 6; ++s) {
    int q = tid + 256*s; int r = q/24, kq = q - r*24;
    ((float4*)Fs)[r*25 + kq] = f4p[(size_t)(rt*64 + r)*96 + g*24 + kq];
  }
  #pragma unroll
  for (int s = 0; s < 9; ++s) {
    int q = tid + 256*s; int o = q/24, kq = q - o*24;
    ((float4*)Wsh)[o*25 + kq] = ((const float4*)wgc)[(size_t)(g*GI + o)*24 + kq];
  }
  __syncthreads();
  float acc[4][6] = {};
  #pragma unroll 4
  for (int k4 = 0; k4 < 24; ++k4) {
    float4 a[4], bv[6];
    #pragma unroll
    for (int i = 0; i < 4; ++i) a[i]  = ((const float4*)Fs)[(tr+16*i)*25 + k4];
    #pragma unroll
    for (int j = 0; j < 6; ++j) bv[j] = ((const float4*)Wsh)[(tc+16*j)*25 + k4];
    #pragma unroll
    for (int i = 0; i < 4; ++i)
      #pragma unroll
      for (int j = 0; j < 6; ++j)
        acc[i][j] += a[i].x*bv[j].x + a[i].y*bv[j].y + a[i].z*bv[j].z + a[i].w*bv[j].w;
  }
  #pragma unroll
  for (int j = 0; j < 6; ++j) {
    float bias = bgc[g*GI + tc + 16*j];
    #pragma unroll
    for (int i = 0; i < 4; ++i)
      y[(size_t)(rt*64 + tr + 16*i)*C2 + g*GI + tc + 16*j] = acc[i][j] + bias;
  }
}

// ---------------- bn + exact gelu, in place ----------------
__global__ void k_bn_gelu(float* __restrict__ y, const float* __restrict__ scale,
                          const float* __restrict__ shift) {
  size_t i = (size_t)blockIdx.x*blockDim.x + threadIdx.x;  // float4 index
  float4 v = ((float4*)y)[i];
  int c4 = (int)(i % 96);
  float4 sc = ((const float4*)scale)[c4], sh = ((const float4*)shift)[c4];
  float vv[4] = {v.x*sc.x+sh.x, v.y*sc.y+sh.y, v.z*sc.z+sh.z, v.w*sc.w+sh.w};
  #pragma unroll
  for (int t = 0; t < 4; ++t)
    vv[t] = 0.5f*vv[t]*(1.0f + erff(vv[t]*0.70710678118654752440f));
  v.x = vv[0]; v.y = vv[1]; v.z = vv[2]; v.w = vv[3];
  ((float4*)y)[i] = v;
}

// ---------------- fc2 ----------------
__global__ __launch_bounds__(256) void k_fc2(const float* __restrict__ y2,
    const float* __restrict__ w2, const float* __restrict__ b2, float* __restrict__ op) {
  __shared__ __align__(16) float As[64*68];
  __shared__ __align__(16) float Wsh[64*68];
  int rt = blockIdx.x, c0 = blockIdx.y*64;
  int tid = threadIdx.x, tc = tid & 15, tr = tid >> 4;
  float acc[4][4] = {};
  for (int kc = 0; kc < 6; ++kc) {
    __syncthreads();
    #pragma unroll
    for (int s = 0; s < 4; ++s) {
      int q = tid + 256*s;
      int r = q >> 4, kq = q & 15;
      ((float4*)As)[r*17 + kq]  = ((const float4*)y2)[(size_t)(rt*64 + r)*96 + kc*16 + kq];
      ((float4*)Wsh)[r*17 + kq] = ((const float4*)w2)[(size_t)(c0 + r)*96 + kc*16 + kq];
    }
    __syncthreads();
    #pragma unroll 4
    for (int k4 = 0; k4 < 16; ++k4) {
      float4 a[4], bv[4];
      #pragma unroll
      for (int i = 0; i < 4; ++i) a[i]  = ((const float4*)As)[(tr+16*i)*17 + k4];
      #pragma unroll
      for (int j = 0; j < 4; ++j) bv[j] = ((const float4*)Wsh)[(tc+16*j)*17 + k4];
      #pragma unroll
      for (int i = 0; i < 4; ++i)
        #pragma unroll
        for (int j = 0; j < 4; ++j)
          acc[i][j] += a[i].x*bv[j].x + a[i].y*bv[j].y + a[i].z*bv[j].z + a[i].w*bv[j].w;
    }
  }
  #pragma unroll
  for (int j = 0; j < 4; ++j) {
    float bias = b2[c0 + tc + 16*j];
    #pragma unroll
    for (int i = 0; i < 4; ++i)
      op[(size_t)(rt*64 + tr + 16*i)*CC + c0 + tc + 16*j] = acc[i][j] + bias;
  }
}

// ---------------- final bn + residual + transpose to (B,C,N) ----------------
__global__ __launch_bounds__(256) void k_final(const float* __restrict__ op,
    const float* __restrict__ x, const float* __restrict__ scale,
    const float* __restrict__ shift, float* __restrict__ out) {
  __shared__ float t[32][33];
  int n0 = blockIdx.x*32, c0 = blockIdx.y*32, b = blockIdx.z;
  int tx = threadIdx.x, ty = threadIdx.y;
  #pragma unroll
  for (int s = 0; s < 4; ++s) {
    int r = ty + 8*s;
    int c = c0 + tx;
    t[r][tx] = op[((size_t)b*NN + n0 + r)*CC + c]*scale[c] + shift[c];
  }
  __syncthreads();
  #pragma unroll
  for (int s = 0; s < 4; ++s) {
    int c = ty + 8*s;
    size_t o = ((size_t)b*CC + c0 + c)*NN + n0 + tx;
    out[o] = t[tx][c] + x[o];
  }
}

extern "C" void kernel_launch(void* const* d_in, const int* in_sizes, int n_in,
                              void* d_out, int out_size, void* d_ws, size_t ws_size,
                              hipStream_t stream) {
  (void)in_sizes; (void)n_in; (void)out_size; (void)ws_size;
  const float* x   = (const float*)d_in[0];
  const float* w1  = (const float*)d_in[1];
  const float* b1  = (const float*)d_in[2];
  const float* g1  = (const float*)d_in[3];
  const float* be1 = (const float*)d_in[4];
  const float* wgc = (const float*)d_in[5];
  const float* bgc = (const float*)d_in[6];
  const float* g2  = (const float*)d_in[7];
  const float* be2 = (const float*)d_in[8];
  const float* w2  = (const float*)d_in[9];
  const float* b2  = (const float*)d_in[10];
  const float* g3  = (const float*)d_in[11];
  const float* be3 = (const float*)d_in[12];
  float* ws = (float*)d_ws;

  // Workspace (floats):
  // h:   [0, 4816896)                 z -> h in place; later reused as op
  // fhi: [4816896, 7225344)           f16 hi
  // flo: [7225344, 9633792)           f16 lo (scaled 2^12)
  // feat:[4816896, 14450688)          aliases fhi/flo (dead after k_dist)
  // sqh: [14450688, 14475776)
  // idx: [14475776, 14701568)
  // part:[14701568, 14898176)
  // st:  [14898176, 14899712)
  float* h    = ws;
  ushortT* fhi = (ushortT*)(ws + 4816896);
  ushortT* flo = (ushortT*)(ws + 7225344);
  float* feat = ws + 4816896;
  float* op   = ws;                        // alias of h region (h dead after k_gather)
  float* sqh  = ws + 14450688;
  int*   idx  = (int*)(ws + 14475776);
  float* part = ws + 14701568;
  float* st   = ws + 14898176;
  float* sc1 = st;        float* sh1 = st + 192;
  float* sc2 = st + 384;  float* sh2 = st + 768;
  float* sc3 = st + 1152; float* sh3 = st + 1344;
  float* out = (float*)d_out;

  k_fc1<<<dim3(49,3,8), 256, 0, stream>>>(x, w1, b1, h);
  k_stats_part<<<NCHUNK, CC, 0, stream>>>(h, CC, part);
  k_stats_fin<<<1, CC, 0, stream>>>(part, CC, g1, be1, sc1, sh1);
  k_h_f<<<NR/4, 256, 0, stream>>>(h, fhi, flo, sqh, sc1, sh1);
  k_dist<<<dim3(200), 256, 0, stream>>>(fhi, flo, sqh, idx);   // id%8 = batch (XCD-affine)
  k_gather<<<NR/4, 256, 0, stream>>>(h, idx, feat);
  k_gconv<<<dim3(392,4), 256, 0, stream>>>(feat, wgc, bgc, feat);   // y in place
  k_stats_part<<<NCHUNK, C2, 0, stream>>>(feat, C2, part);
  k_stats_fin<<<1, C2, 0, stream>>>(part, C2, g2, be2, sc2, sh2);
  k_bn_gelu<<<9408, 256, 0, stream>>>(feat, sc2, sh2);
  k_fc2<<<dim3(392,3), 256, 0, stream>>>(feat, w2, b2, op);
  k_stats_part<<<NCHUNK, CC, 0, stream>>>(op, CC, part);
  k_stats_fin<<<1, CC, 0, stream>>>(part, CC, g3, be3, sc3, sh3);
  k_final<<<dim3(98,6,8), dim3(32,8), 0, stream>>>(op, x, sc3, sh3, out);
}